// Round 1
// baseline (1549.364 us; speedup 1.0000x reference)
//
#include <hip/hip_runtime.h>

// Sinkhorn, 64 x 1024 x 1024 fp32, 20 iterations.
//
// Key identity: log_alpha stays of the form -C/eps - r_i - c_j, so in linear
// domain this is classic Sinkhorn:  K = exp(-C/eps); u = 1/(K v); v = 1/(K^T u);
// out = u_i * K_ij * v_j.  One fused pass over C per iteration (row-dot and
// column-accumulate share the load), tiny fixup kernel for v, one final pass.

#define BATCH 64
#define N 1024
#define NITERS 20
#define ROWS_PER_BLOCK 64
#define BLOCKS_PER_BATCH (N / ROWS_PER_BLOCK)  // 16
#define THREADS 256                            // each thread owns 4 columns (float4)

__device__ __forceinline__ float block_reduce_broadcast(float val, float* lds) {
    // wave(64)-level tree reduce, then 4-wave combine via LDS; result to all threads
    #pragma unroll
    for (int off = 32; off > 0; off >>= 1)
        val += __shfl_xor(val, off, 64);
    const int lane = threadIdx.x & 63;
    const int wid  = threadIdx.x >> 6;
    if (lane == 0) lds[wid] = val;
    __syncthreads();
    float total = lds[0] + lds[1] + lds[2] + lds[3];
    __syncthreads();  // protect lds before next row's writes
    return total;
}

__global__ __launch_bounds__(THREADS) void sink_init(float* __restrict__ v,
                                                     float* __restrict__ colsum) {
    const int i = blockIdx.x * THREADS + threadIdx.x;
    v[i] = 1.0f;       // c_j = 0  <=>  v_j = 1
    colsum[i] = 0.0f;  // ws is poisoned 0xAA before every call
}

// One Sinkhorn iteration, fused: per row  u_i = 1/sum_j K_ij v_j  (old v),
// then colsum_j += K_ij * u_i.  Block = 256 threads x 64 rows of one batch.
__global__ __launch_bounds__(THREADS) void sink_iter(
        const float* __restrict__ C, const float* __restrict__ eps,
        const float* __restrict__ v, float* __restrict__ u,
        float* __restrict__ colsum) {
    __shared__ float lds[4];
    const int t = threadIdx.x;
    const int b = blockIdx.y;
    const int row0 = blockIdx.x * ROWS_PER_BLOCK;
    const float neg_inv_eps = -1.0f / eps[0];

    const float4 vv = ((const float4*)(v + b * N))[t];  // this thread's 4 columns
    const float4* __restrict__ Cp = (const float4*)(C + ((size_t)b * N + row0) * N);

    float4 colacc = make_float4(0.f, 0.f, 0.f, 0.f);
    float4 cur = Cp[t];  // prefetch row 0
    for (int i = 0; i < ROWS_PER_BLOCK; ++i) {
        float4 nxt = cur;
        if (i + 1 < ROWS_PER_BLOCK)
            nxt = Cp[(size_t)(i + 1) * (N / 4) + t];  // issue next-row load before barriers

        float4 k;
        k.x = __expf(cur.x * neg_inv_eps);
        k.y = __expf(cur.y * neg_inv_eps);
        k.z = __expf(cur.z * neg_inv_eps);
        k.w = __expf(cur.w * neg_inv_eps);

        float s = k.x * vv.x + k.y * vv.y + k.z * vv.z + k.w * vv.w;
        float S = block_reduce_broadcast(s, lds);
        float ui = 1.0f / S;
        if (t == 0) u[b * N + row0 + i] = ui;

        colacc.x += k.x * ui;
        colacc.y += k.y * ui;
        colacc.z += k.z * ui;
        colacc.w += k.w * ui;
        cur = nxt;
    }

    float* cs = colsum + b * N + 4 * t;
    atomicAdd(cs + 0, colacc.x);
    atomicAdd(cs + 1, colacc.y);
    atomicAdd(cs + 2, colacc.z);
    atomicAdd(cs + 3, colacc.w);
}

__global__ __launch_bounds__(THREADS) void sink_fix(float* __restrict__ v,
                                                    float* __restrict__ colsum) {
    const int i = blockIdx.x * THREADS + threadIdx.x;
    v[i] = 1.0f / colsum[i];
    colsum[i] = 0.0f;  // ready for next iteration
}

__global__ __launch_bounds__(THREADS) void sink_final(
        const float* __restrict__ C, const float* __restrict__ eps,
        const float* __restrict__ u, const float* __restrict__ v,
        float* __restrict__ out) {
    const int t = threadIdx.x;
    const int row = blockIdx.x;
    const int b = blockIdx.y;
    const float neg_inv_eps = -1.0f / eps[0];
    const float ui = u[b * N + row];
    const float4 vv = ((const float4*)(v + b * N))[t];
    const size_t base = ((size_t)b * N + row) * N;
    float4 c = ((const float4*)(C + base))[t];
    float4 o;
    o.x = __expf(c.x * neg_inv_eps) * ui * vv.x;
    o.y = __expf(c.y * neg_inv_eps) * ui * vv.y;
    o.z = __expf(c.z * neg_inv_eps) * ui * vv.z;
    o.w = __expf(c.w * neg_inv_eps) * ui * vv.w;
    ((float4*)(out + base))[t] = o;
}

extern "C" void kernel_launch(void* const* d_in, const int* in_sizes, int n_in,
                              void* d_out, int out_size, void* d_ws, size_t ws_size,
                              hipStream_t stream) {
    const float* C   = (const float*)d_in[0];
    const float* eps = (const float*)d_in[1];
    float* out = (float*)d_out;

    // workspace layout: u | v | colsum  (3 x 64K floats = 768 KB)
    float* u      = (float*)d_ws;
    float* v      = u + BATCH * N;
    float* colsum = v + BATCH * N;

    sink_init<<<dim3(BATCH * N / THREADS), dim3(THREADS), 0, stream>>>(v, colsum);
    for (int it = 0; it < NITERS; ++it) {
        sink_iter<<<dim3(BLOCKS_PER_BATCH, BATCH), dim3(THREADS), 0, stream>>>(
            C, eps, v, u, colsum);
        sink_fix<<<dim3(BATCH * N / THREADS), dim3(THREADS), 0, stream>>>(v, colsum);
    }
    sink_final<<<dim3(N, BATCH), dim3(THREADS), 0, stream>>>(C, eps, u, v, out);
}

// Round 2
// 1116.069 us; speedup vs baseline: 1.3882x; 1.3882x over previous
//
#include <hip/hip_runtime.h>
#include <hip/hip_fp16.h>

// Sinkhorn, 64 x 1024 x 1024 fp32, 20 iterations.
//
// Linear-domain identity: K = exp(-C/eps); u = 1/(K v); v = 1/(K^T u);
// out = u_i K_ij v_j.
//
// This version caches K as fp16 in d_ws (134 MB, fits the 256 MiB L3):
//  - build kernel: read C (fp32), write K (fp16), do iteration 1 (v=1) fused
//  - 19 iter kernels: read fp16 K only (L3-resident), fused row+col pass
//  - colsum ping-pong across 20 pre-zeroed buffers (no fix kernels)
//  - final: out = u * K * v from fp16 K
// Falls back to the all-fp32 path if ws_size is too small.

#define BATCH 64
#define N 1024
#define NITERS 20
#define ROWS_PER_BLOCK 64
#define BLOCKS_PER_BATCH (N / ROWS_PER_BLOCK)  // 16
#define THREADS 256
#define NU2 (N / 4)  // uint2 (4 halves) per row = 256

// ---------- fp16 pack/unpack helpers ----------
union H2U { __half2 h; unsigned u; };

__device__ __forceinline__ uint2 f4_to_h4(float4 f) {
    H2U a, b;
    a.h = __float22half2_rn(make_float2(f.x, f.y));
    b.h = __float22half2_rn(make_float2(f.z, f.w));
    uint2 r; r.x = a.u; r.y = b.u;
    return r;
}

__device__ __forceinline__ float4 h4_to_f4(uint2 r) {
    H2U a, b;
    a.u = r.x; b.u = r.y;
    float2 fa = __half22float2(a.h);
    float2 fb = __half22float2(b.h);
    return make_float4(fa.x, fa.y, fb.x, fb.y);
}

// ---------- cached-K path ----------

// zero the 20 colsum ping-pong buffers
__global__ __launch_bounds__(THREADS) void sk_zero(float* __restrict__ csum_all) {
    const int i = blockIdx.x * THREADS + threadIdx.x;
    csum_all[i] = 0.0f;
}

// Iteration 1 fused with K construction. v = 1 (no csum_in).
__global__ __launch_bounds__(THREADS) void sk_build(
        const float* __restrict__ C, const float* __restrict__ eps,
        uint2* __restrict__ K, float* __restrict__ u,
        float* __restrict__ csum_out) {
    __shared__ float lds[2][4][8];
    const int t = threadIdx.x;
    const int b = blockIdx.y;
    const int row0 = blockIdx.x * ROWS_PER_BLOCK;
    const int lane = t & 63, wid = t >> 6;
    const float nie = -1.0f / eps[0];

    const float4* __restrict__ Cp = (const float4*)(C + ((size_t)b * N + row0) * N) + t;
    uint2* __restrict__ Kp = K + ((size_t)b * N + row0) * NU2 + t;

    float4 colacc = make_float4(0.f, 0.f, 0.f, 0.f);
    float4 cur[8];
    #pragma unroll
    for (int r = 0; r < 8; ++r) cur[r] = Cp[r * 256];

    for (int chunk = 0; chunk < 8; ++chunk) {
        float4 nxt[8];
        if (chunk < 7) {
            #pragma unroll
            for (int r = 0; r < 8; ++r) nxt[r] = Cp[(chunk * 8 + 8 + r) * 256];
        }
        float4 k[8]; float s[8];
        #pragma unroll
        for (int r = 0; r < 8; ++r) {
            k[r].x = __expf(cur[r].x * nie);
            k[r].y = __expf(cur[r].y * nie);
            k[r].z = __expf(cur[r].z * nie);
            k[r].w = __expf(cur[r].w * nie);
            s[r] = (k[r].x + k[r].y) + (k[r].z + k[r].w);  // v = 1
            Kp[(chunk * 8 + r) * NU2] = f4_to_h4(k[r]);
        }
        #pragma unroll
        for (int off = 32; off; off >>= 1)
            #pragma unroll
            for (int r = 0; r < 8; ++r) s[r] += __shfl_xor(s[r], off, 64);
        const int p = chunk & 1;
        if (lane == 0) {
            #pragma unroll
            for (int r = 0; r < 8; ++r) lds[p][wid][r] = s[r];
        }
        __syncthreads();
        float ui[8];
        #pragma unroll
        for (int r = 0; r < 8; ++r)
            ui[r] = 1.0f / (((lds[p][0][r] + lds[p][1][r]) + (lds[p][2][r] + lds[p][3][r])));
        if (t < 8)
            u[b * N + row0 + chunk * 8 + t] =
                1.0f / ((lds[p][0][t] + lds[p][1][t]) + (lds[p][2][t] + lds[p][3][t]));
        #pragma unroll
        for (int r = 0; r < 8; ++r) {
            colacc.x += k[r].x * ui[r];
            colacc.y += k[r].y * ui[r];
            colacc.z += k[r].z * ui[r];
            colacc.w += k[r].w * ui[r];
        }
        #pragma unroll
        for (int r = 0; r < 8; ++r) cur[r] = nxt[r];
    }
    float* cs = csum_out + b * N + 4 * t;
    atomicAdd(cs + 0, colacc.x);
    atomicAdd(cs + 1, colacc.y);
    atomicAdd(cs + 2, colacc.z);
    atomicAdd(cs + 3, colacc.w);
}

// One Sinkhorn iteration from fp16 K. v = 1/csum_in (inverted on load).
__global__ __launch_bounds__(THREADS) void sk_iter(
        const uint2* __restrict__ K, const float* __restrict__ csum_in,
        float* __restrict__ u, float* __restrict__ csum_out) {
    __shared__ float lds[2][4][8];
    const int t = threadIdx.x;
    const int b = blockIdx.y;
    const int row0 = blockIdx.x * ROWS_PER_BLOCK;
    const int lane = t & 63, wid = t >> 6;

    const float4 ci = ((const float4*)(csum_in + b * N))[t];
    const float4 vv = make_float4(1.0f / ci.x, 1.0f / ci.y, 1.0f / ci.z, 1.0f / ci.w);
    const uint2* __restrict__ Kp = K + ((size_t)b * N + row0) * NU2 + t;

    float4 colacc = make_float4(0.f, 0.f, 0.f, 0.f);
    uint2 cur[8];
    #pragma unroll
    for (int r = 0; r < 8; ++r) cur[r] = Kp[r * NU2];

    for (int chunk = 0; chunk < 8; ++chunk) {
        uint2 nxt[8];
        if (chunk < 7) {
            #pragma unroll
            for (int r = 0; r < 8; ++r) nxt[r] = Kp[(chunk * 8 + 8 + r) * NU2];
        }
        float4 k[8]; float s[8];
        #pragma unroll
        for (int r = 0; r < 8; ++r) {
            k[r] = h4_to_f4(cur[r]);
            s[r] = (k[r].x * vv.x + k[r].y * vv.y) + (k[r].z * vv.z + k[r].w * vv.w);
        }
        #pragma unroll
        for (int off = 32; off; off >>= 1)
            #pragma unroll
            for (int r = 0; r < 8; ++r) s[r] += __shfl_xor(s[r], off, 64);
        const int p = chunk & 1;
        if (lane == 0) {
            #pragma unroll
            for (int r = 0; r < 8; ++r) lds[p][wid][r] = s[r];
        }
        __syncthreads();
        float ui[8];
        #pragma unroll
        for (int r = 0; r < 8; ++r)
            ui[r] = 1.0f / (((lds[p][0][r] + lds[p][1][r]) + (lds[p][2][r] + lds[p][3][r])));
        if (t < 8)
            u[b * N + row0 + chunk * 8 + t] =
                1.0f / ((lds[p][0][t] + lds[p][1][t]) + (lds[p][2][t] + lds[p][3][t]));
        #pragma unroll
        for (int r = 0; r < 8; ++r) {
            colacc.x += k[r].x * ui[r];
            colacc.y += k[r].y * ui[r];
            colacc.z += k[r].z * ui[r];
            colacc.w += k[r].w * ui[r];
        }
        #pragma unroll
        for (int r = 0; r < 8; ++r) cur[r] = nxt[r];
    }
    float* cs = csum_out + b * N + 4 * t;
    atomicAdd(cs + 0, colacc.x);
    atomicAdd(cs + 1, colacc.y);
    atomicAdd(cs + 2, colacc.z);
    atomicAdd(cs + 3, colacc.w);
}

__global__ __launch_bounds__(THREADS) void sk_final(
        const uint2* __restrict__ K, const float* __restrict__ u,
        const float* __restrict__ csum_last, float* __restrict__ out) {
    const int t = threadIdx.x;
    const int row = blockIdx.x;
    const int b = blockIdx.y;
    const float ui = u[b * N + row];
    const float4 ci = ((const float4*)(csum_last + b * N))[t];
    const float4 vv = make_float4(1.0f / ci.x, 1.0f / ci.y, 1.0f / ci.z, 1.0f / ci.w);
    const size_t base = (size_t)b * N + row;
    float4 k = h4_to_f4((K + base * NU2)[t]);
    float4 o;
    o.x = k.x * ui * vv.x;
    o.y = k.y * ui * vv.y;
    o.z = k.z * ui * vv.z;
    o.w = k.w * ui * vv.w;
    ((float4*)(out + base * N))[t] = o;
}

// ---------- fallback all-fp32 path (round-1, known-good) ----------

__device__ __forceinline__ float block_reduce_broadcast(float val, float* lds) {
    #pragma unroll
    for (int off = 32; off > 0; off >>= 1)
        val += __shfl_xor(val, off, 64);
    const int lane = threadIdx.x & 63;
    const int wid  = threadIdx.x >> 6;
    if (lane == 0) lds[wid] = val;
    __syncthreads();
    float total = lds[0] + lds[1] + lds[2] + lds[3];
    __syncthreads();
    return total;
}

__global__ __launch_bounds__(THREADS) void sink_init(float* __restrict__ v,
                                                     float* __restrict__ colsum) {
    const int i = blockIdx.x * THREADS + threadIdx.x;
    v[i] = 1.0f;
    colsum[i] = 0.0f;
}

__global__ __launch_bounds__(THREADS) void sink_iter(
        const float* __restrict__ C, const float* __restrict__ eps,
        const float* __restrict__ v, float* __restrict__ u,
        float* __restrict__ colsum) {
    __shared__ float lds[4];
    const int t = threadIdx.x;
    const int b = blockIdx.y;
    const int row0 = blockIdx.x * ROWS_PER_BLOCK;
    const float neg_inv_eps = -1.0f / eps[0];

    const float4 vv = ((const float4*)(v + b * N))[t];
    const float4* __restrict__ Cp = (const float4*)(C + ((size_t)b * N + row0) * N);

    float4 colacc = make_float4(0.f, 0.f, 0.f, 0.f);
    float4 cur = Cp[t];
    for (int i = 0; i < ROWS_PER_BLOCK; ++i) {
        float4 nxt = cur;
        if (i + 1 < ROWS_PER_BLOCK)
            nxt = Cp[(size_t)(i + 1) * (N / 4) + t];

        float4 k;
        k.x = __expf(cur.x * neg_inv_eps);
        k.y = __expf(cur.y * neg_inv_eps);
        k.z = __expf(cur.z * neg_inv_eps);
        k.w = __expf(cur.w * neg_inv_eps);

        float s = k.x * vv.x + k.y * vv.y + k.z * vv.z + k.w * vv.w;
        float S = block_reduce_broadcast(s, lds);
        float ui = 1.0f / S;
        if (t == 0) u[b * N + row0 + i] = ui;

        colacc.x += k.x * ui;
        colacc.y += k.y * ui;
        colacc.z += k.z * ui;
        colacc.w += k.w * ui;
        cur = nxt;
    }

    float* cs = colsum + b * N + 4 * t;
    atomicAdd(cs + 0, colacc.x);
    atomicAdd(cs + 1, colacc.y);
    atomicAdd(cs + 2, colacc.z);
    atomicAdd(cs + 3, colacc.w);
}

__global__ __launch_bounds__(THREADS) void sink_fix(float* __restrict__ v,
                                                    float* __restrict__ colsum) {
    const int i = blockIdx.x * THREADS + threadIdx.x;
    v[i] = 1.0f / colsum[i];
    colsum[i] = 0.0f;
}

__global__ __launch_bounds__(THREADS) void sink_final(
        const float* __restrict__ C, const float* __restrict__ eps,
        const float* __restrict__ u, const float* __restrict__ v,
        float* __restrict__ out) {
    const int t = threadIdx.x;
    const int row = blockIdx.x;
    const int b = blockIdx.y;
    const float neg_inv_eps = -1.0f / eps[0];
    const float ui = u[b * N + row];
    const float4 vv = ((const float4*)(v + b * N))[t];
    const size_t base = ((size_t)b * N + row) * N;
    float4 c = ((const float4*)(C + base))[t];
    float4 o;
    o.x = __expf(c.x * neg_inv_eps) * ui * vv.x;
    o.y = __expf(c.y * neg_inv_eps) * ui * vv.y;
    o.z = __expf(c.z * neg_inv_eps) * ui * vv.z;
    o.w = __expf(c.w * neg_inv_eps) * ui * vv.w;
    ((float4*)(out + base))[t] = o;
}

// ---------- launch ----------

extern "C" void kernel_launch(void* const* d_in, const int* in_sizes, int n_in,
                              void* d_out, int out_size, void* d_ws, size_t ws_size,
                              hipStream_t stream) {
    const float* C   = (const float*)d_in[0];
    const float* eps = (const float*)d_in[1];
    float* out = (float*)d_out;

    const size_t k_bytes  = (size_t)BATCH * N * N * 2;        // fp16 K: 134 MB
    const size_t uv_elems = (size_t)BATCH * N;                // 64K floats
    const size_t needed   = k_bytes + uv_elems * 4 * (1 + NITERS);

    if (ws_size >= needed) {
        uint2* K      = (uint2*)d_ws;
        float* u      = (float*)((char*)d_ws + k_bytes);
        float* csum   = u + uv_elems;  // 20 buffers of 64K floats, csum[t-1] for iter t

        // zero all 20 colsum buffers (ws is poisoned 0xAA before every call)
        sk_zero<<<dim3(NITERS * uv_elems / THREADS), dim3(THREADS), 0, stream>>>(csum);
        // iteration 1 fused with K build (v = 1)
        sk_build<<<dim3(BLOCKS_PER_BATCH, BATCH), dim3(THREADS), 0, stream>>>(
            C, eps, K, u, csum);
        // iterations 2..20
        for (int it = 2; it <= NITERS; ++it) {
            sk_iter<<<dim3(BLOCKS_PER_BATCH, BATCH), dim3(THREADS), 0, stream>>>(
                K, csum + (size_t)(it - 2) * uv_elems, u,
                csum + (size_t)(it - 1) * uv_elems);
        }
        sk_final<<<dim3(N, BATCH), dim3(THREADS), 0, stream>>>(
            K, u, csum + (size_t)(NITERS - 1) * uv_elems, out);
    } else {
        // fallback: all-fp32 path
        float* u      = (float*)d_ws;
        float* v      = u + uv_elems;
        float* colsum = v + uv_elems;
        sink_init<<<dim3(BATCH * N / THREADS), dim3(THREADS), 0, stream>>>(v, colsum);
        for (int it = 0; it < NITERS; ++it) {
            sink_iter<<<dim3(BLOCKS_PER_BATCH, BATCH), dim3(THREADS), 0, stream>>>(
                C, eps, v, u, colsum);
            sink_fix<<<dim3(BATCH * N / THREADS), dim3(THREADS), 0, stream>>>(v, colsum);
        }
        sink_final<<<dim3(N, BATCH), dim3(THREADS), 0, stream>>>(C, eps, u, v, out);
    }
}